// Round 4
// baseline (340.192 us; speedup 1.0000x reference)
//
#include <hip/hip_runtime.h>
#include <math.h>
#include <stdint.h>

#define NUM_CL 21
#define NB 4
#define H 512
#define W 512
#define PH 171
#define PW 171
#define PWPAD 176
#define NHH 169
#define NWW 169
#define M_TOT (NHH*NWW)          // 28561
#define NCP (NB*NUM_CL)          // 84
#define ACC_PER 189
#define POS_ALPHA 5e-4
#define NBLKA (NB*NUM_CL*PH)     // 14364
#define NCHUNK 11                // col chunks: 10x16 + 1x9
#define ITEMS (NHH*NCHUNK)       // 1859
#define BSLICE 8                 // 8*256 = 2048 >= 1859

typedef unsigned long long u64;
typedef unsigned int u32;

__device__ __forceinline__ int upIdx(int lo, int hi) {
    return lo*9 - (lo*(lo-1))/2 + (hi - lo);
}
__device__ __forceinline__ int tri(int d, int e) { return d*(d+1)/2 + e; }

// ---------------- Kernel 0: labels int -> uchar + valid count ----------------
__global__ __launch_bounds__(256) void kernel0(
    const int* __restrict__ labels, unsigned char* __restrict__ lab8,
    u64* __restrict__ validCnt)
{
    int idx = blockIdx.x * 256 + threadIdx.x;   // over NB*H*W/4 int4s
    int4 l = ((const int4*)labels)[idx];
    uchar4 u;
    u.x = (l.x < NUM_CL) ? (unsigned char)l.x : 255;
    u.y = (l.y < NUM_CL) ? (unsigned char)l.y : 255;
    u.z = (l.z < NUM_CL) ? (unsigned char)l.z : 255;
    u.w = (l.w < NUM_CL) ? (unsigned char)l.w : 255;
    ((uchar4*)lab8)[idx] = u;
    u32 cnt = (l.x < NUM_CL) + (l.y < NUM_CL) + (l.z < NUM_CL) + (l.w < NUM_CL);
    #pragma unroll
    for (int o = 32; o > 0; o >>= 1) cnt += __shfl_down(cnt, o, 64);
    if ((threadIdx.x & 63) == 0) atomicAdd(validCnt, (u64)cnt);
}

// ---------------- Kernel A: fused sigmoid + BCE + 3x3/3 max-pool ----------------
// One block per (n, c, pooled-row ph). pooledP has padded stride PWPAD;
// pooled labels written as bit-plane (4 u64 per row) via ballot.
__global__ __launch_bounds__(128) void kernelA(
    const float* __restrict__ logits, const unsigned char* __restrict__ lab8,
    float* __restrict__ pooledP, u64* __restrict__ Lbits,
    float* __restrict__ bce_part)
{
    int blk = blockIdx.x;
    int c  = blk % NUM_CL;
    int t2 = blk / NUM_CL;
    int ph = t2 % PH;
    int n  = t2 / PH;
    int tid = threadIdx.x;           // 0..127
    int col0 = tid << 2;

    __shared__ float         svP[W];
    __shared__ unsigned char svL[W];
    __shared__ float         rbce[2];

    const float* lgp = logits + (size_t)(n*NUM_CL + c) * (H*W);
    const unsigned char* lbp = lab8 + (size_t)n * (H*W);

    float vP[4] = {-INFINITY, -INFINITY, -INFINITY, -INFINITY};
    int   vL[4] = {0,0,0,0};
    float bce = 0.f;

    int rbase = 3*ph - 1;
    #pragma unroll
    for (int rr = 0; rr < 3; ++rr) {
        int r = rbase + rr;
        if (r < 0 || r >= H) continue;       // uniform across block
        float4 x4 = *(const float4*)(lgp + (size_t)r*W + col0);
        uchar4 l4 = *(const uchar4*)(lbp + (size_t)r*W + col0);
        float xs[4] = {x4.x, x4.y, x4.z, x4.w};
        int   ls[4] = {l4.x, l4.y, l4.z, l4.w};
        #pragma unroll
        for (int k = 0; k < 4; ++k) {
            int lab = ls[k];
            float x = xs[k];
            float m = (lab < NUM_CL) ? 1.f : 0.f;
            float y = (lab == c) ? 1.f : 0.f;
            float te = __expf(-fabsf(x));
            float u  = 1.f + te;
            float sp = __logf(u);                    // log1p(te)
            float rc = __builtin_amdgcn_rcpf(u);     // 1/(1+te)
            bce += m * (fmaxf(x, 0.f) - x*y + sp);
            float sig = (x >= 0.f) ? rc : te*rc;
            vP[k] = fmaxf(vP[k], sig*m + 1e-6f);
            vL[k] |= (lab == c);
        }
    }

    ((float4*)svP)[tid] = make_float4(vP[0], vP[1], vP[2], vP[3]);
    uchar4 u4;
    u4.x = (unsigned char)vL[0]; u4.y = (unsigned char)vL[1];
    u4.z = (unsigned char)vL[2]; u4.w = (unsigned char)vL[3];
    ((uchar4*)svL)[tid] = u4;

    // wave-level BCE reduction (2 waves)
    #pragma unroll
    for (int o = 32; o > 0; o >>= 1) bce += __shfl_down(bce, o, 64);
    int lane = tid & 63, wv = tid >> 6;
    if (lane == 0) rbce[wv] = bce;
    __syncthreads();

    // horizontal pool from LDS; label bits via ballot
    size_t rowr = (size_t)(n*NUM_CL + c) * PH + ph;
    #pragma unroll
    for (int pass = 0; pass < 2; ++pass) {
        int pw = tid + pass*128;
        int lm = 0;
        if (pw < PW) {
            int c0 = 3*pw - 1; if (c0 < 0) c0 = 0;
            int c1 = 3*pw + 2; if (c1 > W) c1 = W;
            float pm = -INFINITY;
            for (int qq = c0; qq < c1; ++qq) {
                pm = fmaxf(pm, svP[qq]);
                lm |= svL[qq];
            }
            pooledP[rowr * PWPAD + pw] = pm;
        }
        u64 bal = __ballot(lm != 0);
        if (lane == 0) Lbits[rowr * 4 + (pw >> 6)] = bal;
    }

    if (tid == 0) bce_part[blk] = rbce[0] + rbce[1];
}

// ---------------- Kernel B helpers ----------------
template<int NWIN>
__device__ __forceinline__ void loadStrip(const float* __restrict__ P,
                                          const u64* __restrict__ Lb,
                                          int i, int j0,
                                          float s[3][NWIN+2], u32 m[3])
{
    constexpr int NC = NWIN + 2;
    #pragma unroll
    for (int r = 0; r < 3; ++r) {
        const float* rp = P + (size_t)(i + r) * PWPAD + j0;
        #pragma unroll
        for (int q = 0; q < NC/4; ++q) {
            float4 v = *(const float4*)(rp + 4*q);
            s[r][4*q+0] = v.x; s[r][4*q+1] = v.y; s[r][4*q+2] = v.z; s[r][4*q+3] = v.w;
        }
        #pragma unroll
        for (int q = (NC/4)*4; q < NC; ++q) s[r][q] = rp[q];
        const u64* lw = Lb + (size_t)(i + r) * 4 + (j0 >> 6);
        int sh = j0 & 63;
        u64 lo = (lw[0] >> sh) | ((lw[1] << 1) << (63 - sh));
        m[r] = (u32)lo & 0x3FFFFu;
    }
}

// group 0: sp, cpp, sl, cll
template<int NWIN>
__device__ __forceinline__ void bodyPP(const float* __restrict__ P,
                                       const u64* __restrict__ Lb,
                                       int i, int j0,
                                       float sp[9], float cpp[45],
                                       int sl[9], int cll[45])
{
    float s[3][NWIN+2]; u32 m[3];
    loadStrip<NWIN>(P, Lb, i, j0, s, m);
    #pragma unroll
    for (int w = 0; w < NWIN; ++w) {
        float pv[9];
        #pragma unroll
        for (int d = 0; d < 9; ++d) pv[d] = s[d/3][w + d%3];
        #pragma unroll
        for (int d = 0; d < 9; ++d) sp[d] += pv[d];
        int k = 0;
        #pragma unroll
        for (int d = 0; d < 9; ++d)
            #pragma unroll
            for (int e = d; e < 9; ++e) { cpp[k] += pv[d]*pv[e]; ++k; }
    }
    constexpr u32 WM = (1u << NWIN) - 1;
    #pragma unroll
    for (int d = 0; d < 9; ++d) sl[d] += __popc((m[d/3] >> (d%3)) & WM);
    int k = 0;
    #pragma unroll
    for (int d = 0; d < 9; ++d) {
        u32 md = m[d/3] >> (d%3);
        #pragma unroll
        for (int e = d; e < 9; ++e) { cll[k] += __popc(md & (m[e/3] >> (e%3)) & WM); ++k; }
    }
}

// group 1: clp[d][e] = sum la_d * pr_e
template<int NWIN>
__device__ __forceinline__ void bodyLP(const float* __restrict__ P,
                                       const u64* __restrict__ Lb,
                                       int i, int j0, float clp[81])
{
    float s[3][NWIN+2]; u32 m[3];
    loadStrip<NWIN>(P, Lb, i, j0, s, m);
    #pragma unroll
    for (int w = 0; w < NWIN; ++w) {
        float la[9], pv[9];
        #pragma unroll
        for (int d = 0; d < 9; ++d) {
            pv[d] = s[d/3][w + d%3];
            la[d] = (float)((m[d/3] >> (w + d%3)) & 1u);
        }
        #pragma unroll
        for (int d = 0; d < 9; ++d)
            #pragma unroll
            for (int e = 0; e < 9; ++e) clp[d*9+e] += la[d]*pv[e];
    }
}

__device__ __forceinline__ float wred64(float v) {
    #pragma unroll
    for (int o = 32; o > 0; o >>= 1) v += __shfl_down(v, o, 64);
    return v;
}

// ---------------- Kernel B0: sp, cpp, sl, cll ----------------
__global__ __launch_bounds__(256, 2) void kernelB0(
    const float* __restrict__ pooledP, const u64* __restrict__ Lbits,
    double* __restrict__ cov_acc)
{
    int nc = blockIdx.x;
    int id = blockIdx.y * 256 + threadIdx.x;
    const float* P = pooledP + (size_t)nc * PH * PWPAD;
    const u64*  Lb = Lbits  + (size_t)nc * PH * 4;

    float sp[9], cpp[45];
    int sl[9], cll[45];
    #pragma unroll
    for (int d = 0; d < 9; ++d) { sp[d] = 0.f; sl[d] = 0; }
    #pragma unroll
    for (int k = 0; k < 45; ++k) { cpp[k] = 0.f; cll[k] = 0; }

    if (id < ITEMS) {
        int i = id / NCHUNK;
        int chunk = id - i * NCHUNK;
        int j0 = chunk << 4;
        if (chunk < 10) bodyPP<16>(P, Lb, i, j0, sp, cpp, sl, cll);
        else            bodyPP<9>(P, Lb, i, j0, sp, cpp, sl, cll);
    }

    __shared__ float red[4][108];
    int lane = threadIdx.x & 63, wave = threadIdx.x >> 6;
    #pragma unroll
    for (int d = 0; d < 9; ++d) { float r = wred64((float)sl[d]); if (lane == 0) red[wave][d]    = r; }
    #pragma unroll
    for (int d = 0; d < 9; ++d) { float r = wred64(sp[d]);        if (lane == 0) red[wave][9+d]  = r; }
    #pragma unroll
    for (int k = 0; k < 45; ++k) { float r = wred64((float)cll[k]); if (lane == 0) red[wave][18+k] = r; }
    #pragma unroll
    for (int k = 0; k < 45; ++k) { float r = wred64(cpp[k]);        if (lane == 0) red[wave][63+k] = r; }
    __syncthreads();
    double* acc = cov_acc + (size_t)nc * ACC_PER;
    for (int v = threadIdx.x; v < 108; v += 256) {
        float sum = red[0][v] + red[1][v] + red[2][v] + red[3][v];
        atomicAdd(&acc[v], (double)sum);
    }
}

// ---------------- Kernel B1: clp ----------------
__global__ __launch_bounds__(256, 2) void kernelB1(
    const float* __restrict__ pooledP, const u64* __restrict__ Lbits,
    double* __restrict__ cov_acc)
{
    int nc = blockIdx.x;
    int id = blockIdx.y * 256 + threadIdx.x;
    const float* P = pooledP + (size_t)nc * PH * PWPAD;
    const u64*  Lb = Lbits  + (size_t)nc * PH * 4;

    float clp[81];
    #pragma unroll
    for (int k = 0; k < 81; ++k) clp[k] = 0.f;

    if (id < ITEMS) {
        int i = id / NCHUNK;
        int chunk = id - i * NCHUNK;
        int j0 = chunk << 4;
        if (chunk < 10) bodyLP<16>(P, Lb, i, j0, clp);
        else            bodyLP<9>(P, Lb, i, j0, clp);
    }

    __shared__ float red[4][81];
    int lane = threadIdx.x & 63, wave = threadIdx.x >> 6;
    #pragma unroll
    for (int k = 0; k < 81; ++k) { float r = wred64(clp[k]); if (lane == 0) red[wave][k] = r; }
    __syncthreads();
    double* acc = cov_acc + (size_t)nc * ACC_PER;
    for (int v = threadIdx.x; v < 81; v += 256) {
        float sum = red[0][v] + red[1][v] + red[2][v] + red[3][v];
        atomicAdd(&acc[108 + v], (double)sum);
    }
}

// ---------------- Kernel C: BCE reduce + per-(n,c) 9x9 solve + combine ----------------
__global__ __launch_bounds__(256) void kernelC(
    const double* __restrict__ cov_acc,
    const float* __restrict__ bce_part,
    const u64* __restrict__ validCnt,
    float* __restrict__ out)
{
    int t = threadIdx.x;

    __shared__ double sb[256];
    double bs = 0.0;
    for (int i = t; i < NBLKA; i += 256) bs += (double)bce_part[i];
    sb[t] = bs;
    __syncthreads();
    #pragma unroll
    for (int s = 128; s > 0; s >>= 1) {
        if (t < s) sb[t] += sb[t + s];
        __syncthreads();
    }

    float contrib = 0.f;
    if (t < NCP) {
        const double* acc = cov_acc + (size_t)t * ACC_PER;
        const double Minv = 1.0 / (double)M_TOT;
        double Sl[9], Sp[9];
        #pragma unroll
        for (int d = 0; d < 9; ++d) { Sl[d] = acc[d]; Sp[d] = acc[9+d]; }

        float A[45];  // pr_cov + alpha*I (lower tri)
        float G[45];  // la_cov, later appro_var
        float B[81];  // la_pr_cov rows, later W rows
        #pragma unroll
        for (int d = 0; d < 9; ++d) {
            #pragma unroll
            for (int e = 0; e <= d; ++e) {
                int ku = upIdx(e, d);
                double vp = acc[63+ku] - Sp[d]*Sp[e]*Minv;
                double vl = acc[18+ku] - Sl[d]*Sl[e]*Minv;
                if (d == e) vp += POS_ALPHA;
                A[tri(d,e)] = (float)vp;
                G[tri(d,e)] = (float)vl;
            }
        }
        #pragma unroll
        for (int d = 0; d < 9; ++d) {
            #pragma unroll
            for (int e = 0; e < 9; ++e)
                B[d*9+e] = (float)(acc[108 + d*9 + e] - Sl[d]*Sp[e]*Minv);
        }

        // Cholesky of A (lower, in place)
        #pragma unroll
        for (int d = 0; d < 9; ++d) {
            float s = A[tri(d,d)];
            #pragma unroll
            for (int f = 0; f < d; ++f) { float v = A[tri(d,f)]; s -= v*v; }
            float ldd = sqrtf(s);
            A[tri(d,d)] = ldd;
            float inv = 1.f / ldd;
            #pragma unroll
            for (int e = d+1; e < 9; ++e) {
                float s2 = A[tri(e,d)];
                #pragma unroll
                for (int f = 0; f < d; ++f) s2 -= A[tri(e,f)] * A[tri(d,f)];
                A[tri(e,d)] = s2 * inv;
            }
        }

        // forward substitution: row d of B <- solve L w = LP[d,:]^T
        #pragma unroll
        for (int d = 0; d < 9; ++d) {
            #pragma unroll
            for (int e = 0; e < 9; ++e) {
                float s = B[d*9+e];
                #pragma unroll
                for (int f = 0; f < e; ++f) s -= A[tri(e,f)] * B[d*9+f];
                B[d*9+e] = s / A[tri(e,e)];
            }
        }

        // appro_var = la_cov - W W^T + alpha*I
        #pragma unroll
        for (int d = 0; d < 9; ++d) {
            #pragma unroll
            for (int g = 0; g <= d; ++g) {
                float qv = 0.f;
                #pragma unroll
                for (int e = 0; e < 9; ++e) qv += B[d*9+e] * B[g*9+e];
                float v = G[tri(d,g)] - qv;
                if (d == g) v += (float)POS_ALPHA;
                G[tri(d,g)] = v;
            }
        }

        // Cholesky of G, sum log(diag + 1e-8)
        float sumlog = 0.f;
        #pragma unroll
        for (int d = 0; d < 9; ++d) {
            float s = G[tri(d,d)];
            #pragma unroll
            for (int f = 0; f < d; ++f) { float v = G[tri(d,f)]; s -= v*v; }
            float ldd = sqrtf(s);
            G[tri(d,d)] = ldd;
            sumlog += logf(ldd + 1e-8f);
            float inv = 1.f / ldd;
            #pragma unroll
            for (int e = d+1; e < 9; ++e) {
                float s2 = G[tri(e,d)];
                #pragma unroll
                for (int f = 0; f < d; ++f) s2 -= G[tri(e,f)] * G[tri(d,f)];
                G[tri(e,d)] = s2 * inv;
            }
        }
        contrib = sumlog * (1.0f / 36.0f);   // /(N * HALF_D) = /(4*9)
    }

    __shared__ float sred[256];
    sred[t] = contrib;
    __syncthreads();
    #pragma unroll
    for (int s = 128; s > 0; s >>= 1) {
        if (t < s) sred[t] += sred[t + s];
        __syncthreads();
    }
    if (t == 0) {
        double bce_loss = sb[0] / ((double)validCnt[0] + 1.0);
        out[0] = (float)(0.5 * bce_loss + 0.5 * (double)sred[0]);
    }
}

extern "C" void kernel_launch(void* const* d_in, const int* in_sizes, int n_in,
                              void* d_out, int out_size, void* d_ws, size_t ws_size,
                              hipStream_t stream)
{
    (void)in_sizes; (void)n_in; (void)out_size; (void)ws_size;
    const float* logits = (const float*)d_in[0];
    const int*   labels = (const int*)d_in[1];
    float* out = (float*)d_out;

    uint8_t* w = (uint8_t*)d_ws;
    size_t off = 0;
    double* cov_acc = (double*)(w + off);      off += (size_t)NCP * ACC_PER * 8;   // 127008
    u64* validCnt = (u64*)(w + off);           off += 8;                            // 127016
    float* bce_part = (float*)(w + off);       off += (size_t)NBLKA * 4;            // +57456
    off = (off + 15) & ~(size_t)15;
    float* pooledP = (float*)(w + off);        off += (size_t)NCP * PH * PWPAD * 4; // 10.1 MB
    u64* Lbits = (u64*)(w + off);              off += (size_t)NCP * PH * 4 * 8;     // 459 KB
    unsigned char* lab8 = (unsigned char*)(w + off); off += (size_t)NB * H * W;     // 1 MB

    hipMemsetAsync(d_ws, 0, (size_t)NCP * ACC_PER * 8 + 8, stream);

    kernel0<<<(NB*H*W/4 + 255)/256, 256, 0, stream>>>(labels, lab8, validCnt);
    kernelA<<<NBLKA, 128, 0, stream>>>(logits, lab8, pooledP, Lbits, bce_part);
    kernelB0<<<dim3(NCP, BSLICE), 256, 0, stream>>>(pooledP, Lbits, cov_acc);
    kernelB1<<<dim3(NCP, BSLICE), 256, 0, stream>>>(pooledP, Lbits, cov_acc);
    kernelC<<<1, 256, 0, stream>>>(cov_acc, bce_part, validCnt, out);
}

// Round 5
// 259.410 us; speedup vs baseline: 1.3114x; 1.3114x over previous
//
#include <hip/hip_runtime.h>
#include <math.h>
#include <stdint.h>

#define NUM_CL 21
#define NB 4
#define H 512
#define W 512
#define PH 171
#define PW 171
#define PWPAD 176
#define NHH 169
#define NWW 169
#define M_TOT (NHH*NWW)          // 28561
#define NCP (NB*NUM_CL)          // 84
#define ACC_PER 189
#define POS_ALPHA 5e-4
#define NBLKA (NB*NUM_CL*PH)     // 14364
#define SEGR 43                  // rows per segment (4 segs: 43,43,43,40)

typedef unsigned long long u64;
typedef unsigned int u32;

__device__ __forceinline__ int upIdx(int lo, int hi) {
    return lo*9 - (lo*(lo-1))/2 + (hi - lo);
}
__device__ __forceinline__ int tri(int d, int e) { return d*(d+1)/2 + e; }

__device__ __forceinline__ float wred64(float v) {
    #pragma unroll
    for (int o = 32; o > 0; o >>= 1) v += __shfl_down(v, o, 64);
    return v;
}

// ---------------- Kernel 0: labels int -> uchar + valid count ----------------
__global__ __launch_bounds__(256) void kernel0(
    const int* __restrict__ labels, unsigned char* __restrict__ lab8,
    u64* __restrict__ validCnt)
{
    int idx = blockIdx.x * 256 + threadIdx.x;   // over NB*H*W/4 int4s
    int4 l = ((const int4*)labels)[idx];
    uchar4 u;
    u.x = (l.x < NUM_CL) ? (unsigned char)l.x : 255;
    u.y = (l.y < NUM_CL) ? (unsigned char)l.y : 255;
    u.z = (l.z < NUM_CL) ? (unsigned char)l.z : 255;
    u.w = (l.w < NUM_CL) ? (unsigned char)l.w : 255;
    ((uchar4*)lab8)[idx] = u;
    u32 cnt = (l.x < NUM_CL) + (l.y < NUM_CL) + (l.z < NUM_CL) + (l.w < NUM_CL);
    #pragma unroll
    for (int o = 32; o > 0; o >>= 1) cnt += __shfl_down(cnt, o, 64);
    if ((threadIdx.x & 63) == 0) atomicAdd(validCnt, (u64)cnt);
}

// ---------------- Kernel A: fused sigmoid + BCE + 3x3/3 max-pool ----------------
__global__ __launch_bounds__(128) void kernelA(
    const float* __restrict__ logits, const unsigned char* __restrict__ lab8,
    float* __restrict__ pooledP, float* __restrict__ pooledLf,
    float* __restrict__ bce_part)
{
    int blk = blockIdx.x;
    int c  = blk % NUM_CL;
    int t2 = blk / NUM_CL;
    int ph = t2 % PH;
    int n  = t2 / PH;
    int tid = threadIdx.x;           // 0..127
    int col0 = tid << 2;

    __shared__ float         svP[W];
    __shared__ unsigned char svL[W];
    __shared__ float         rbce[2];

    const float* lgp = logits + (size_t)(n*NUM_CL + c) * (H*W);
    const unsigned char* lbp = lab8 + (size_t)n * (H*W);

    float vP[4] = {-INFINITY, -INFINITY, -INFINITY, -INFINITY};
    int   vL[4] = {0,0,0,0};
    float bce = 0.f;

    int rbase = 3*ph - 1;
    #pragma unroll
    for (int rr = 0; rr < 3; ++rr) {
        int r = rbase + rr;
        if (r < 0 || r >= H) continue;       // uniform across block
        float4 x4 = *(const float4*)(lgp + (size_t)r*W + col0);
        uchar4 l4 = *(const uchar4*)(lbp + (size_t)r*W + col0);
        float xs[4] = {x4.x, x4.y, x4.z, x4.w};
        int   ls[4] = {l4.x, l4.y, l4.z, l4.w};
        #pragma unroll
        for (int k = 0; k < 4; ++k) {
            int lab = ls[k];
            float x = xs[k];
            float m = (lab < NUM_CL) ? 1.f : 0.f;
            float y = (lab == c) ? 1.f : 0.f;
            float te = __expf(-fabsf(x));
            float u  = 1.f + te;
            float sp = __logf(u);                    // log1p(te)
            float rc = __builtin_amdgcn_rcpf(u);     // 1/(1+te)
            bce += m * (fmaxf(x, 0.f) - x*y + sp);
            float sig = (x >= 0.f) ? rc : te*rc;
            vP[k] = fmaxf(vP[k], sig*m + 1e-6f);
            vL[k] |= (lab == c);
        }
    }

    ((float4*)svP)[tid] = make_float4(vP[0], vP[1], vP[2], vP[3]);
    uchar4 u4;
    u4.x = (unsigned char)vL[0]; u4.y = (unsigned char)vL[1];
    u4.z = (unsigned char)vL[2]; u4.w = (unsigned char)vL[3];
    ((uchar4*)svL)[tid] = u4;

    // wave-level BCE reduction (2 waves)
    #pragma unroll
    for (int o = 32; o > 0; o >>= 1) bce += __shfl_down(bce, o, 64);
    int lane = tid & 63, wv = tid >> 6;
    if (lane == 0) rbce[wv] = bce;
    __syncthreads();

    // horizontal pool from LDS
    size_t rowr = (size_t)(n*NUM_CL + c) * PH + ph;
    #pragma unroll
    for (int pass = 0; pass < 2; ++pass) {
        int pw = tid + pass*128;
        if (pw < PW) {
            int c0 = 3*pw - 1; if (c0 < 0) c0 = 0;
            int c1 = 3*pw + 2; if (c1 > W) c1 = W;
            float pm = -INFINITY;
            int lm = 0;
            for (int qq = c0; qq < c1; ++qq) {
                pm = fmaxf(pm, svP[qq]);
                lm |= svL[qq];
            }
            pooledP [rowr * PWPAD + pw] = pm;
            pooledLf[rowr * PWPAD + pw] = (float)lm;
        }
    }

    if (tid == 0) bce_part[blk] = rbce[0] + rbce[1];
}

// ---------------- block reduce (4 waves) + f64 atomic ----------------
template<int CNT>
__device__ __forceinline__ void blockReduceAtomic(
    float (&v)[CNT], double* __restrict__ acc, int accOff, bool active,
    int lane, int wave)
{
    __shared__ float red[4][CNT];
    #pragma unroll
    for (int k = 0; k < CNT; ++k) {
        float r = wred64(active ? v[k] : 0.f);
        if (lane == 0) red[wave][k] = r;
    }
    __syncthreads();
    for (int k = (int)threadIdx.x; k < CNT; k += 256) {
        float s = red[0][k] + red[1][k] + red[2][k] + red[3][k];
        atomicAdd(&acc[accOff + k], (double)s);
    }
    __syncthreads();
}

// ---------------- Kernel B: rolling-window raw-moment accumulation ----------------
// block = 256 (4 waves); wave = row-segment; lane -> window column j.
// grid = (NCP, 3 col-chunks, 2 groups). No per-thread arrays with dynamic
// indices -> everything register-resident.
__global__ __launch_bounds__(256, 1) void kernelB(
    const float* __restrict__ pooledP, const float* __restrict__ pooledLf,
    double* __restrict__ cov_acc)
{
    int nc    = blockIdx.x;
    int chunk = blockIdx.y;          // 0..2
    int grp   = blockIdx.z;          // 0..1
    int lane  = threadIdx.x & 63;
    int seg   = threadIdx.x >> 6;    // 0..3
    int j     = chunk*64 + lane;
    bool active = (j < NWW);
    int jc = active ? j : (NWW - 1); // clamped, loads stay in-bounds
    int i0 = seg * SEGR;
    int i1 = (seg == 3) ? NWW : (i0 + SEGR);

    const float* P = pooledP  + (size_t)nc * PH * PWPAD + jc;
    const float* L = pooledLf + (size_t)nc * PH * PWPAD + jc;
    double* acc = cov_acc + (size_t)nc * ACC_PER;

    float pA[3], pB[3], lA[3], lB[3];
    #pragma unroll
    for (int t = 0; t < 3; ++t) {
        pA[t] = P[(size_t)i0 * PWPAD + t];
        lA[t] = L[(size_t)i0 * PWPAD + t];
        pB[t] = P[(size_t)(i0+1) * PWPAD + t];
        lB[t] = L[(size_t)(i0+1) * PWPAD + t];
    }

    if (grp == 0) {
        float sl[9], sp[9], cll[45], cpp[45];
        #pragma unroll
        for (int d = 0; d < 9; ++d) { sl[d] = 0.f; sp[d] = 0.f; }
        #pragma unroll
        for (int k = 0; k < 45; ++k) { cll[k] = 0.f; cpp[k] = 0.f; }

        for (int i = i0; i < i1; ++i) {
            const float* rp = P + (size_t)(i+2) * PWPAD;
            const float* rl = L + (size_t)(i+2) * PWPAD;
            float pC[3] = {rp[0], rp[1], rp[2]};
            float lC[3] = {rl[0], rl[1], rl[2]};
            float pv[9] = {pA[0],pA[1],pA[2], pB[0],pB[1],pB[2], pC[0],pC[1],pC[2]};
            float lv[9] = {lA[0],lA[1],lA[2], lB[0],lB[1],lB[2], lC[0],lC[1],lC[2]};
            #pragma unroll
            for (int d = 0; d < 9; ++d) { sp[d] += pv[d]; sl[d] += lv[d]; }
            int k = 0;
            #pragma unroll
            for (int d = 0; d < 9; ++d)
                #pragma unroll
                for (int e = d; e < 9; ++e) {
                    cpp[k] += pv[d]*pv[e];
                    cll[k] += lv[d]*lv[e];
                    ++k;
                }
            #pragma unroll
            for (int t = 0; t < 3; ++t) {
                pA[t] = pB[t]; pB[t] = pC[t];
                lA[t] = lB[t]; lB[t] = lC[t];
            }
        }
        blockReduceAtomic<9> (sl,  acc, 0,  active, lane, seg);
        blockReduceAtomic<9> (sp,  acc, 9,  active, lane, seg);
        blockReduceAtomic<45>(cll, acc, 18, active, lane, seg);
        blockReduceAtomic<45>(cpp, acc, 63, active, lane, seg);
    } else {
        float clp[81];
        #pragma unroll
        for (int k = 0; k < 81; ++k) clp[k] = 0.f;

        for (int i = i0; i < i1; ++i) {
            const float* rp = P + (size_t)(i+2) * PWPAD;
            const float* rl = L + (size_t)(i+2) * PWPAD;
            float pC[3] = {rp[0], rp[1], rp[2]};
            float lC[3] = {rl[0], rl[1], rl[2]};
            float pv[9] = {pA[0],pA[1],pA[2], pB[0],pB[1],pB[2], pC[0],pC[1],pC[2]};
            float lv[9] = {lA[0],lA[1],lA[2], lB[0],lB[1],lB[2], lC[0],lC[1],lC[2]};
            #pragma unroll
            for (int d = 0; d < 9; ++d)
                #pragma unroll
                for (int e = 0; e < 9; ++e)
                    clp[d*9+e] += lv[d]*pv[e];
            #pragma unroll
            for (int t = 0; t < 3; ++t) {
                pA[t] = pB[t]; pB[t] = pC[t];
                lA[t] = lB[t]; lB[t] = lC[t];
            }
        }
        blockReduceAtomic<81>(clp, acc, 108, active, lane, seg);
    }
}

// ---------------- Kernel C: BCE reduce + per-(n,c) 9x9 solve + combine ----------------
__global__ __launch_bounds__(256) void kernelC(
    const double* __restrict__ cov_acc,
    const float* __restrict__ bce_part,
    const u64* __restrict__ validCnt,
    float* __restrict__ out)
{
    int t = threadIdx.x;

    __shared__ double sb[256];
    double bs = 0.0;
    for (int i = t; i < NBLKA; i += 256) bs += (double)bce_part[i];
    sb[t] = bs;
    __syncthreads();
    #pragma unroll
    for (int s = 128; s > 0; s >>= 1) {
        if (t < s) sb[t] += sb[t + s];
        __syncthreads();
    }

    float contrib = 0.f;
    if (t < NCP) {
        const double* acc = cov_acc + (size_t)t * ACC_PER;
        const double Minv = 1.0 / (double)M_TOT;
        double Sl[9], Sp[9];
        #pragma unroll
        for (int d = 0; d < 9; ++d) { Sl[d] = acc[d]; Sp[d] = acc[9+d]; }

        float A[45];  // pr_cov + alpha*I (lower tri)
        float G[45];  // la_cov, later appro_var
        float B[81];  // la_pr_cov rows, later W rows
        #pragma unroll
        for (int d = 0; d < 9; ++d) {
            #pragma unroll
            for (int e = 0; e <= d; ++e) {
                int ku = upIdx(e, d);
                double vp = acc[63+ku] - Sp[d]*Sp[e]*Minv;
                double vl = acc[18+ku] - Sl[d]*Sl[e]*Minv;
                if (d == e) vp += POS_ALPHA;
                A[tri(d,e)] = (float)vp;
                G[tri(d,e)] = (float)vl;
            }
        }
        #pragma unroll
        for (int d = 0; d < 9; ++d) {
            #pragma unroll
            for (int e = 0; e < 9; ++e)
                B[d*9+e] = (float)(acc[108 + d*9 + e] - Sl[d]*Sp[e]*Minv);
        }

        // Cholesky of A (lower, in place)
        #pragma unroll
        for (int d = 0; d < 9; ++d) {
            float s = A[tri(d,d)];
            #pragma unroll
            for (int f = 0; f < d; ++f) { float v = A[tri(d,f)]; s -= v*v; }
            float ldd = sqrtf(s);
            A[tri(d,d)] = ldd;
            float inv = 1.f / ldd;
            #pragma unroll
            for (int e = d+1; e < 9; ++e) {
                float s2 = A[tri(e,d)];
                #pragma unroll
                for (int f = 0; f < d; ++f) s2 -= A[tri(e,f)] * A[tri(d,f)];
                A[tri(e,d)] = s2 * inv;
            }
        }

        // forward substitution: row d of B <- solve L w = LP[d,:]^T
        #pragma unroll
        for (int d = 0; d < 9; ++d) {
            #pragma unroll
            for (int e = 0; e < 9; ++e) {
                float s = B[d*9+e];
                #pragma unroll
                for (int f = 0; f < e; ++f) s -= A[tri(e,f)] * B[d*9+f];
                B[d*9+e] = s / A[tri(e,e)];
            }
        }

        // appro_var = la_cov - W W^T + alpha*I
        #pragma unroll
        for (int d = 0; d < 9; ++d) {
            #pragma unroll
            for (int g = 0; g <= d; ++g) {
                float qv = 0.f;
                #pragma unroll
                for (int e = 0; e < 9; ++e) qv += B[d*9+e] * B[g*9+e];
                float v = G[tri(d,g)] - qv;
                if (d == g) v += (float)POS_ALPHA;
                G[tri(d,g)] = v;
            }
        }

        // Cholesky of G, sum log(diag + 1e-8)
        float sumlog = 0.f;
        #pragma unroll
        for (int d = 0; d < 9; ++d) {
            float s = G[tri(d,d)];
            #pragma unroll
            for (int f = 0; f < d; ++f) { float v = G[tri(d,f)]; s -= v*v; }
            float ldd = sqrtf(s);
            G[tri(d,d)] = ldd;
            sumlog += logf(ldd + 1e-8f);
            float inv = 1.f / ldd;
            #pragma unroll
            for (int e = d+1; e < 9; ++e) {
                float s2 = G[tri(e,d)];
                #pragma unroll
                for (int f = 0; f < d; ++f) s2 -= G[tri(e,f)] * G[tri(d,f)];
                G[tri(e,d)] = s2 * inv;
            }
        }
        contrib = sumlog * (1.0f / 36.0f);   // /(N * HALF_D) = /(4*9)
    }

    __shared__ float sred[256];
    sred[t] = contrib;
    __syncthreads();
    #pragma unroll
    for (int s = 128; s > 0; s >>= 1) {
        if (t < s) sred[t] += sred[t + s];
        __syncthreads();
    }
    if (t == 0) {
        double bce_loss = sb[0] / ((double)validCnt[0] + 1.0);
        out[0] = (float)(0.5 * bce_loss + 0.5 * (double)sred[0]);
    }
}

extern "C" void kernel_launch(void* const* d_in, const int* in_sizes, int n_in,
                              void* d_out, int out_size, void* d_ws, size_t ws_size,
                              hipStream_t stream)
{
    (void)in_sizes; (void)n_in; (void)out_size; (void)ws_size;
    const float* logits = (const float*)d_in[0];
    const int*   labels = (const int*)d_in[1];
    float* out = (float*)d_out;

    uint8_t* w = (uint8_t*)d_ws;
    size_t off = 0;
    double* cov_acc = (double*)(w + off);      off += (size_t)NCP * ACC_PER * 8;   // 127008
    u64* validCnt = (u64*)(w + off);           off += 8;
    float* bce_part = (float*)(w + off);       off += (size_t)NBLKA * 4;
    off = (off + 15) & ~(size_t)15;
    float* pooledP = (float*)(w + off);        off += (size_t)NCP * PH * PWPAD * 4; // 10.1 MB
    float* pooledLf = (float*)(w + off);       off += (size_t)NCP * PH * PWPAD * 4; // 10.1 MB
    unsigned char* lab8 = (unsigned char*)(w + off); off += (size_t)NB * H * W;     // 1 MB

    hipMemsetAsync(d_ws, 0, (size_t)NCP * ACC_PER * 8 + 8, stream);

    kernel0<<<(NB*H*W/4 + 255)/256, 256, 0, stream>>>(labels, lab8, validCnt);
    kernelA<<<NBLKA, 128, 0, stream>>>(logits, lab8, pooledP, pooledLf, bce_part);
    kernelB<<<dim3(NCP, 3, 2), 256, 0, stream>>>(pooledP, pooledLf, cov_acc);
    kernelC<<<1, 256, 0, stream>>>(cov_acc, bce_part, validCnt, out);
}

// Round 6
// 205.683 us; speedup vs baseline: 1.6540x; 1.2612x over previous
//
#include <hip/hip_runtime.h>
#include <math.h>
#include <stdint.h>

#define NUM_CL 21
#define NB 4
#define H 512
#define W 512
#define PH 171
#define PW 171
#define PWPAD 176
#define NHH 169
#define NWW 169
#define M_TOT (NHH*NWW)          // 28561
#define NCP (NB*NUM_CL)          // 84
#define ACC_PER 189
#define POS_ALPHA 5e-4
#define NBLKA (NB*NUM_CL*PH)     // 14364
#define NROWBLK (NB*PH)          // 684
#define SEGR 43                  // rows per segment (4 segs: 43,43,43,40)

typedef unsigned long long u64;
typedef unsigned int u32;

__device__ __forceinline__ int upIdx(int lo, int hi) {
    return lo*9 - (lo*(lo-1))/2 + (hi - lo);
}
__device__ __forceinline__ int tri(int d, int e) { return d*(d+1)/2 + e; }

__device__ __forceinline__ float wred64(float v) {
    #pragma unroll
    for (int o = 32; o > 0; o >>= 1) v += __shfl_down(v, o, 64);
    return v;
}

// ---------------- Kernel A: fused sigmoid + BCE + 3x3/3 max-pool ----------------
// One block per (n, c, pooled-row ph). Reads int32 labels directly (L2-resident
// across the 21-class reuse). No global atomics: per-block BCE partials; blocks
// with c==0 also write the per-(n,ph) valid-pixel count partial.
__global__ __launch_bounds__(128) void kernelA(
    const float* __restrict__ logits, const int* __restrict__ labels,
    float* __restrict__ pooledP, float* __restrict__ pooledLf,
    float* __restrict__ bce_part, u32* __restrict__ cnt_part)
{
    int blk = blockIdx.x;
    int c  = blk % NUM_CL;
    int t2 = blk / NUM_CL;
    int ph = t2 % PH;
    int n  = t2 / PH;
    int tid = threadIdx.x;           // 0..127
    int col0 = tid << 2;

    __shared__ float         svP[W];
    __shared__ unsigned char svL[W];
    __shared__ float         rbce[2];
    __shared__ u32           rcnt[2];

    const float* lgp = logits + (size_t)(n*NUM_CL + c) * (H*W);
    const int*   lbp = labels + (size_t)n * (H*W);

    float vP[4] = {-INFINITY, -INFINITY, -INFINITY, -INFINITY};
    int   vL[4] = {0,0,0,0};
    float bce = 0.f;
    u32 cnt = 0;

    int rbase = 3*ph - 1;
    #pragma unroll
    for (int rr = 0; rr < 3; ++rr) {
        int r = rbase + rr;
        if (r < 0 || r >= H) continue;       // uniform across block
        float4 x4 = *(const float4*)(lgp + (size_t)r*W + col0);
        int4   l4 = *(const int4*)  (lbp + (size_t)r*W + col0);
        float xs[4] = {x4.x, x4.y, x4.z, x4.w};
        int   ls[4] = {l4.x, l4.y, l4.z, l4.w};
        #pragma unroll
        for (int k = 0; k < 4; ++k) {
            int lab = ls[k];
            float x = xs[k];
            float m = (lab < NUM_CL) ? 1.f : 0.f;
            float y = (lab == c) ? 1.f : 0.f;
            float te = __expf(-fabsf(x));
            float u  = 1.f + te;
            float sp = __logf(u);                    // log1p(te)
            float rc = __builtin_amdgcn_rcpf(u);     // 1/(1+te)
            bce += m * (fmaxf(x, 0.f) - x*y + sp);
            float sig = (x >= 0.f) ? rc : te*rc;
            vP[k] = fmaxf(vP[k], sig*m + 1e-6f);
            vL[k] |= (lab == c);
            cnt += (u32)(lab < NUM_CL);
        }
    }

    ((float4*)svP)[tid] = make_float4(vP[0], vP[1], vP[2], vP[3]);
    uchar4 u4;
    u4.x = (unsigned char)vL[0]; u4.y = (unsigned char)vL[1];
    u4.z = (unsigned char)vL[2]; u4.w = (unsigned char)vL[3];
    ((uchar4*)svL)[tid] = u4;

    // wave-level BCE/count reduction (2 waves)
    #pragma unroll
    for (int o = 32; o > 0; o >>= 1) {
        bce += __shfl_down(bce, o, 64);
        cnt += __shfl_down(cnt, o, 64);
    }
    int lane = tid & 63, wv = tid >> 6;
    if (lane == 0) { rbce[wv] = bce; rcnt[wv] = cnt; }
    __syncthreads();

    // horizontal pool from LDS
    size_t rowr = (size_t)(n*NUM_CL + c) * PH + ph;
    #pragma unroll
    for (int pass = 0; pass < 2; ++pass) {
        int pw = tid + pass*128;
        if (pw < PW) {
            int c0 = 3*pw - 1; if (c0 < 0) c0 = 0;
            int c1 = 3*pw + 2; if (c1 > W) c1 = W;
            float pm = -INFINITY;
            int lm = 0;
            for (int qq = c0; qq < c1; ++qq) {
                pm = fmaxf(pm, svP[qq]);
                lm |= svL[qq];
            }
            pooledP [rowr * PWPAD + pw] = pm;
            pooledLf[rowr * PWPAD + pw] = (float)lm;
        }
    }

    if (tid == 0) {
        bce_part[blk] = rbce[0] + rbce[1];
        if (c == 0) cnt_part[t2] = rcnt[0] + rcnt[1];
    }
}

// ---------------- block reduce (4 waves) + f64 atomic ----------------
template<int CNT>
__device__ __forceinline__ void blockReduceAtomic(
    float (&v)[CNT], double* __restrict__ acc, int accOff, bool active,
    int lane, int wave)
{
    __shared__ float red[4][CNT];
    #pragma unroll
    for (int k = 0; k < CNT; ++k) {
        float r = wred64(active ? v[k] : 0.f);
        if (lane == 0) red[wave][k] = r;
    }
    __syncthreads();
    for (int k = (int)threadIdx.x; k < CNT; k += 256) {
        float s = red[0][k] + red[1][k] + red[2][k] + red[3][k];
        atomicAdd(&acc[accOff + k], (double)s);
    }
    __syncthreads();
}

// ---------------- Kernel B: rolling-window raw-moment accumulation ----------------
// block = 256 (4 waves); wave = row-segment; lane -> window column j.
// grid = (NCP, 3 col-chunks, 2 groups). No per-thread arrays with dynamic
// indices -> everything register-resident.
__global__ __launch_bounds__(256, 1) void kernelB(
    const float* __restrict__ pooledP, const float* __restrict__ pooledLf,
    double* __restrict__ cov_acc)
{
    int nc    = blockIdx.x;
    int chunk = blockIdx.y;          // 0..2
    int grp   = blockIdx.z;          // 0..1
    int lane  = threadIdx.x & 63;
    int seg   = threadIdx.x >> 6;    // 0..3
    int j     = chunk*64 + lane;
    bool active = (j < NWW);
    int jc = active ? j : (NWW - 1); // clamped, loads stay in-bounds
    int i0 = seg * SEGR;
    int i1 = (seg == 3) ? NWW : (i0 + SEGR);

    const float* P = pooledP  + (size_t)nc * PH * PWPAD + jc;
    const float* L = pooledLf + (size_t)nc * PH * PWPAD + jc;
    double* acc = cov_acc + (size_t)nc * ACC_PER;

    float pA[3], pB[3], lA[3], lB[3];
    #pragma unroll
    for (int t = 0; t < 3; ++t) {
        pA[t] = P[(size_t)i0 * PWPAD + t];
        lA[t] = L[(size_t)i0 * PWPAD + t];
        pB[t] = P[(size_t)(i0+1) * PWPAD + t];
        lB[t] = L[(size_t)(i0+1) * PWPAD + t];
    }

    if (grp == 0) {
        float sl[9], sp[9], cll[45], cpp[45];
        #pragma unroll
        for (int d = 0; d < 9; ++d) { sl[d] = 0.f; sp[d] = 0.f; }
        #pragma unroll
        for (int k = 0; k < 45; ++k) { cll[k] = 0.f; cpp[k] = 0.f; }

        for (int i = i0; i < i1; ++i) {
            const float* rp = P + (size_t)(i+2) * PWPAD;
            const float* rl = L + (size_t)(i+2) * PWPAD;
            float pC[3] = {rp[0], rp[1], rp[2]};
            float lC[3] = {rl[0], rl[1], rl[2]};
            float pv[9] = {pA[0],pA[1],pA[2], pB[0],pB[1],pB[2], pC[0],pC[1],pC[2]};
            float lv[9] = {lA[0],lA[1],lA[2], lB[0],lB[1],lB[2], lC[0],lC[1],lC[2]};
            #pragma unroll
            for (int d = 0; d < 9; ++d) { sp[d] += pv[d]; sl[d] += lv[d]; }
            int k = 0;
            #pragma unroll
            for (int d = 0; d < 9; ++d)
                #pragma unroll
                for (int e = d; e < 9; ++e) {
                    cpp[k] += pv[d]*pv[e];
                    cll[k] += lv[d]*lv[e];
                    ++k;
                }
            #pragma unroll
            for (int t = 0; t < 3; ++t) {
                pA[t] = pB[t]; pB[t] = pC[t];
                lA[t] = lB[t]; lB[t] = lC[t];
            }
        }
        blockReduceAtomic<9> (sl,  acc, 0,  active, lane, seg);
        blockReduceAtomic<9> (sp,  acc, 9,  active, lane, seg);
        blockReduceAtomic<45>(cll, acc, 18, active, lane, seg);
        blockReduceAtomic<45>(cpp, acc, 63, active, lane, seg);
    } else {
        float clp[81];
        #pragma unroll
        for (int k = 0; k < 81; ++k) clp[k] = 0.f;

        for (int i = i0; i < i1; ++i) {
            const float* rp = P + (size_t)(i+2) * PWPAD;
            const float* rl = L + (size_t)(i+2) * PWPAD;
            float pC[3] = {rp[0], rp[1], rp[2]};
            float lC[3] = {rl[0], rl[1], rl[2]};
            float pv[9] = {pA[0],pA[1],pA[2], pB[0],pB[1],pB[2], pC[0],pC[1],pC[2]};
            float lv[9] = {lA[0],lA[1],lA[2], lB[0],lB[1],lB[2], lC[0],lC[1],lC[2]};
            #pragma unroll
            for (int d = 0; d < 9; ++d)
                #pragma unroll
                for (int e = 0; e < 9; ++e)
                    clp[d*9+e] += lv[d]*pv[e];
            #pragma unroll
            for (int t = 0; t < 3; ++t) {
                pA[t] = pB[t]; pB[t] = pC[t];
                lA[t] = lB[t]; lB[t] = lC[t];
            }
        }
        blockReduceAtomic<81>(clp, acc, 108, active, lane, seg);
    }
}

// ---------------- Kernel C: BCE/count reduce + per-(n,c) 9x9 solve + combine ----------------
__global__ __launch_bounds__(256) void kernelC(
    const double* __restrict__ cov_acc,
    const float* __restrict__ bce_part,
    const u32* __restrict__ cnt_part,
    float* __restrict__ out)
{
    int t = threadIdx.x;

    __shared__ double sb[256];
    __shared__ u32 sc[256];
    double bs = 0.0;
    for (int i = t; i < NBLKA; i += 256) bs += (double)bce_part[i];
    u32 cs = 0;
    for (int i = t; i < NROWBLK; i += 256) cs += cnt_part[i];
    sb[t] = bs; sc[t] = cs;
    __syncthreads();
    #pragma unroll
    for (int s = 128; s > 0; s >>= 1) {
        if (t < s) { sb[t] += sb[t + s]; sc[t] += sc[t + s]; }
        __syncthreads();
    }

    float contrib = 0.f;
    if (t < NCP) {
        const double* acc = cov_acc + (size_t)t * ACC_PER;
        const double Minv = 1.0 / (double)M_TOT;
        double Sl[9], Sp[9];
        #pragma unroll
        for (int d = 0; d < 9; ++d) { Sl[d] = acc[d]; Sp[d] = acc[9+d]; }

        float A[45];  // pr_cov + alpha*I (lower tri)
        float G[45];  // la_cov, later appro_var
        float B[81];  // la_pr_cov rows, later W rows
        #pragma unroll
        for (int d = 0; d < 9; ++d) {
            #pragma unroll
            for (int e = 0; e <= d; ++e) {
                int ku = upIdx(e, d);
                double vp = acc[63+ku] - Sp[d]*Sp[e]*Minv;
                double vl = acc[18+ku] - Sl[d]*Sl[e]*Minv;
                if (d == e) vp += POS_ALPHA;
                A[tri(d,e)] = (float)vp;
                G[tri(d,e)] = (float)vl;
            }
        }
        #pragma unroll
        for (int d = 0; d < 9; ++d) {
            #pragma unroll
            for (int e = 0; e < 9; ++e)
                B[d*9+e] = (float)(acc[108 + d*9 + e] - Sl[d]*Sp[e]*Minv);
        }

        // Cholesky of A (lower, in place)
        #pragma unroll
        for (int d = 0; d < 9; ++d) {
            float s = A[tri(d,d)];
            #pragma unroll
            for (int f = 0; f < d; ++f) { float v = A[tri(d,f)]; s -= v*v; }
            float ldd = sqrtf(s);
            A[tri(d,d)] = ldd;
            float inv = 1.f / ldd;
            #pragma unroll
            for (int e = d+1; e < 9; ++e) {
                float s2 = A[tri(e,d)];
                #pragma unroll
                for (int f = 0; f < d; ++f) s2 -= A[tri(e,f)] * A[tri(d,f)];
                A[tri(e,d)] = s2 * inv;
            }
        }

        // forward substitution: row d of B <- solve L w = LP[d,:]^T
        #pragma unroll
        for (int d = 0; d < 9; ++d) {
            #pragma unroll
            for (int e = 0; e < 9; ++e) {
                float s = B[d*9+e];
                #pragma unroll
                for (int f = 0; f < e; ++f) s -= A[tri(e,f)] * B[d*9+f];
                B[d*9+e] = s / A[tri(e,e)];
            }
        }

        // appro_var = la_cov - W W^T + alpha*I
        #pragma unroll
        for (int d = 0; d < 9; ++d) {
            #pragma unroll
            for (int g = 0; g <= d; ++g) {
                float qv = 0.f;
                #pragma unroll
                for (int e = 0; e < 9; ++e) qv += B[d*9+e] * B[g*9+e];
                float v = G[tri(d,g)] - qv;
                if (d == g) v += (float)POS_ALPHA;
                G[tri(d,g)] = v;
            }
        }

        // Cholesky of G, sum log(diag + 1e-8)
        float sumlog = 0.f;
        #pragma unroll
        for (int d = 0; d < 9; ++d) {
            float s = G[tri(d,d)];
            #pragma unroll
            for (int f = 0; f < d; ++f) { float v = G[tri(d,f)]; s -= v*v; }
            float ldd = sqrtf(s);
            G[tri(d,d)] = ldd;
            sumlog += logf(ldd + 1e-8f);
            float inv = 1.f / ldd;
            #pragma unroll
            for (int e = d+1; e < 9; ++e) {
                float s2 = G[tri(e,d)];
                #pragma unroll
                for (int f = 0; f < d; ++f) s2 -= G[tri(e,f)] * G[tri(d,f)];
                G[tri(e,d)] = s2 * inv;
            }
        }
        contrib = sumlog * (1.0f / 36.0f);   // /(N * HALF_D) = /(4*9)
    }

    __shared__ float sred[256];
    sred[t] = contrib;
    __syncthreads();
    #pragma unroll
    for (int s = 128; s > 0; s >>= 1) {
        if (t < s) sred[t] += sred[t + s];
        __syncthreads();
    }
    if (t == 0) {
        double bce_loss = sb[0] / ((double)sc[0] + 1.0);
        out[0] = (float)(0.5 * bce_loss + 0.5 * (double)sred[0]);
    }
}

extern "C" void kernel_launch(void* const* d_in, const int* in_sizes, int n_in,
                              void* d_out, int out_size, void* d_ws, size_t ws_size,
                              hipStream_t stream)
{
    (void)in_sizes; (void)n_in; (void)out_size; (void)ws_size;
    const float* logits = (const float*)d_in[0];
    const int*   labels = (const int*)d_in[1];
    float* out = (float*)d_out;

    uint8_t* w = (uint8_t*)d_ws;
    size_t off = 0;
    double* cov_acc = (double*)(w + off);      off += (size_t)NCP * ACC_PER * 8;   // 127008
    float* bce_part = (float*)(w + off);       off += (size_t)NBLKA * 4;
    u32* cnt_part = (u32*)(w + off);           off += (size_t)NROWBLK * 4;
    off = (off + 15) & ~(size_t)15;
    float* pooledP = (float*)(w + off);        off += (size_t)NCP * PH * PWPAD * 4; // 10.1 MB
    float* pooledLf = (float*)(w + off);       off += (size_t)NCP * PH * PWPAD * 4; // 10.1 MB

    hipMemsetAsync(cov_acc, 0, (size_t)NCP * ACC_PER * 8, stream);

    kernelA<<<NBLKA, 128, 0, stream>>>(logits, labels, pooledP, pooledLf, bce_part, cnt_part);
    kernelB<<<dim3(NCP, 3, 2), 256, 0, stream>>>(pooledP, pooledLf, cov_acc);
    kernelC<<<1, 256, 0, stream>>>(cov_acc, bce_part, cnt_part, out);
}